// Round 12
// baseline (213.270 us; speedup 1.0000x reference)
//
#include <hip/hip_runtime.h>
#include <stdint.h>
#include <math.h>

typedef unsigned short u16;
typedef unsigned long long ull;

// Problem constants (B=16, N=M=4096, D=3)
#define NPTS  4096
#define NB    16
#define NRES  12288               // residuals per (batch, direction)
#define NPAIR 32                  // 16 batches x 2 directions
#define G     16                  // grid cells per axis
#define NCELL 4096                // G^3
#define HCEL  0.0625f             // 1/G
#define MARGIN 1e-5f
// 0-indexed order-statistic ranks for jnp.quantile(0.15/0.85, linear)
#define RANK_LO 1843u
#define RANK_HI 10443u

// LDS layout (single 121.25 KB block, 1 block/CU)
#define OFF_TGT   0               // float4[4096]  = 65536
#define OFF_CST   65536           // u16[4160]     = 8320  -> 73856
#define OFF_KBUF  73856           // u32[12288]    = 49152 -> 123008 (aliases build hist)
#define OFF_DM    123008          // double[96]    = 768   -> 123776
#define OFF_UM    123776          // u32[64]       = 256   -> 124032 (wpart/bc/minred)
#define OFF_IM    124032          // int[32]       = 128   -> 124160
#define SMEM_SZ   124160

__device__ __forceinline__ uint32_t f2key(float f) {
    uint32_t u = __float_as_uint(f);
    return (u & 0x80000000u) ? ~u : (u | 0x80000000u);
}
__device__ __forceinline__ float key2f(uint32_t k) {
    uint32_t u = (k & 0x80000000u) ? (k ^ 0x80000000u) : ~k;
    return __uint_as_float(u);
}

// exclusive prefix over h[0 .. 1024*BPT), 1024 threads / 16 waves
template <int BPT>
__device__ __forceinline__ void scanB(uint32_t* h, uint32_t* wtmp) {
    const int tid = threadIdx.x, lane = tid & 63, wv = tid >> 6;
    const int base = tid * BPT;
    uint32_t loc[BPT], sum = 0;
    #pragma unroll
    for (int j = 0; j < BPT; ++j) { loc[j] = h[base + j]; sum += loc[j]; }
    uint32_t sc = sum;
    #pragma unroll
    for (int off = 1; off < 64; off <<= 1) {
        const uint32_t u = __shfl_up(sc, off);
        if (lane >= off) sc += u;
    }
    if (lane == 63) wtmp[wv] = sc;
    __syncthreads();
    uint32_t wb = 0;
    #pragma unroll
    for (int k = 0; k < 16; ++k) wb += (k < wv) ? wtmp[k] : 0u;
    uint32_t ex = wb + sc - sum;
    #pragma unroll
    for (int j = 0; j < BPT; ++j) { h[base + j] = ex; ex += loc[j]; }
    __syncthreads();
}

// unique bin with h[i] <= r < h[i+1] (exclusive-prefix array)
template <int BPT>
__device__ __forceinline__ void psearchB(const uint32_t* h, int n, uint32_t r,
                                         uint32_t total, uint32_t* out3) {
    const int base = threadIdx.x * BPT;
    #pragma unroll
    for (int j = 0; j < BPT; ++j) {
        const int i = base + j;
        if (i < n) {
            const uint32_t lo = h[i];
            const uint32_t hi = (i + 1 < n) ? h[i + 1] : total;
            if (lo <= r && r < hi) { out3[0] = (uint32_t)i; out3[1] = lo; out3[2] = hi; }
        }
    }
}

// ---------------------------------------------------------------------------
// Fused kernel: one block per (batch, direction). 32 blocks x 1024 threads.
// build (LDS grid) -> query (LDS candidates) -> sigma (LDS keys) -> final.
// ---------------------------------------------------------------------------
__global__ __launch_bounds__(1024) void fused_kernel(const float* __restrict__ x,
                                                     const float* __restrict__ y,
                                                     float* __restrict__ sig,
                                                     unsigned int* __restrict__ counter,
                                                     float* __restrict__ out) {
    __shared__ __align__(16) char smem[SMEM_SZ];
    float4*   tgt  = (float4*)(smem + OFF_TGT);
    u16*      cst  = (u16*)(smem + OFF_CST);
    uint32_t* kbuf = (uint32_t*)(smem + OFF_KBUF);
    double*   dm   = (double*)(smem + OFF_DM);
    uint32_t* um   = (uint32_t*)(smem + OFF_UM);    // [0..15] wpart, [16..27] bc, [28..59] minred
    int*      im   = (int*)(smem + OFF_IM);

    const int pd = blockIdx.x, b = pd >> 1, dir = pd & 1;
    const float* tg = (dir == 0 ? y : x) + (size_t)b * NPTS * 3;   // targets
    const float* qg = (dir == 0 ? x : y) + (size_t)b * NPTS * 3;   // queries
    const int tid = threadIdx.x, lane = tid & 63, wv = tid >> 6;

    // ================= build: counting-sort targets into LDS =================
    uint32_t* hist = kbuf;                    // alias (keys written later)
    #pragma unroll
    for (int j = 0; j < 4; ++j) hist[tid * 4 + j] = 0u;
    __syncthreads();

    float f[12];
    int ci[4];
    {
        const float4* tp4 = reinterpret_cast<const float4*>(tg + (size_t)tid * 12);
        #pragma unroll
        for (int j = 0; j < 3; ++j) {
            const float4 v = tp4[j];
            f[j * 4 + 0] = v.x; f[j * 4 + 1] = v.y; f[j * 4 + 2] = v.z; f[j * 4 + 3] = v.w;
        }
        #pragma unroll
        for (int k = 0; k < 4; ++k) {
            const int cx = (int)(f[k * 3 + 0] * 16.f);
            const int cy = (int)(f[k * 3 + 1] * 16.f);
            const int cz = (int)(f[k * 3 + 2] * 16.f);
            ci[k] = (cx * G + cy) * G + cz;
            atomicAdd(&hist[ci[k]], 1u);
        }
    }
    __syncthreads();
    scanB<4>(hist, um);                       // exclusive prefix of 4096 bins
    for (int i = tid; i <= NCELL; i += 1024)
        cst[i] = (u16)((i == NCELL) ? NPTS : hist[i]);
    __syncthreads();
    #pragma unroll
    for (int k = 0; k < 4; ++k) {
        const float px = f[k * 3 + 0], py = f[k * 3 + 1], pz = f[k * 3 + 2];
        const uint32_t pos = atomicAdd(&hist[ci[k]], 1u);
        const float w = fmaf(pz, pz, fmaf(py, py, px * px));
        tgt[pos] = make_float4(-2.f * px, -2.f * py, -2.f * pz, w);
    }
    __syncthreads();                          // build done; kbuf free for keys

    // ================= query: quad-per-query, candidates from LDS =================
    const int l4 = tid & 3, qg4 = tid >> 2;   // 256 quads
    double s1a = 0.0, s2a = 0.0;

    for (int r = 0; r < 16; ++r) {
        const int qi = r * 256 + qg4;
        const float qx = qg[qi * 3 + 0], qy = qg[qi * 3 + 1], qz = qg[qi * 3 + 2];
        const float qq = fmaf(qz, qz, fmaf(qy, qy, qx * qx));   // same chain as build w
        const int cx = (int)(qx * 16.f), cy = (int)(qy * 16.f), cz = (int)(qz * 16.f);

        ull pk = ~0ull;
        {   // 9 clamped z-runs (border duplicates harmless for min)
            const int zlo = max(cz - 1, 0), zhi = min(cz + 1, G - 1);
            #define RUNB(RR, AV, NV)                                              \
                int AV, NV;                                                       \
                { const int ix = min(max(cx + (RR) / 3 - 1, 0), G - 1);           \
                  const int iy = min(max(cy + (RR) % 3 - 1, 0), G - 1);           \
                  const int cc = (ix * G + iy) * G;                               \
                  AV = cst[cc + zlo];                                             \
                  NV = cst[cc + zhi + 1] - AV; }
            RUNB(0, a0, n0) RUNB(1, a1, n1) RUNB(2, a2, n2)
            RUNB(3, a3, n3) RUNB(4, a4, n4) RUNB(5, a5, n5)
            RUNB(6, a6, n6) RUNB(7, a7, n7) RUNB(8, a8, n8)
            #undef RUNB
            const int nc = n0 + n1 + n2 + n3 + n4 + n5 + n6 + n7 + n8;
            for (int li = l4; li < nc; li += 4) {
                int pos;
                {
                    int rem = li; pos = a0 + rem;
                    rem -= n0; pos = (rem >= 0) ? a1 + rem : pos;
                    rem -= n1; pos = (rem >= 0) ? a2 + rem : pos;
                    rem -= n2; pos = (rem >= 0) ? a3 + rem : pos;
                    rem -= n3; pos = (rem >= 0) ? a4 + rem : pos;
                    rem -= n4; pos = (rem >= 0) ? a5 + rem : pos;
                    rem -= n5; pos = (rem >= 0) ? a6 + rem : pos;
                    rem -= n6; pos = (rem >= 0) ? a7 + rem : pos;
                    rem -= n7; pos = (rem >= 0) ? a8 + rem : pos;
                    pos = min(pos, NPTS - 1);
                }
                const float4 T = tgt[pos];
                const float d = fmaf(qx, T.x, fmaf(qy, T.y, fmaf(qz, T.z, T.w)));
                const ull cand = ((ull)f2key(d) << 32) | (uint32_t)pos;
                pk = (cand < pk) ? cand : pk;
            }
        }
        {   // quad min-reduce
            ull o = __shfl_xor(pk, 1); pk = (o < pk) ? o : pk;
            o = __shfl_xor(pk, 2);     pk = (o < pk) ? o : pk;
        }
        // shell expansion while min possible distance could beat current best
        for (int s = 2; s <= G - 1; ++s) {
            const float bd = key2f((uint32_t)(pk >> 32));
            const float dmin = (float)(s - 1) * HCEL;
            if (fmaf(dmin, dmin, -(bd + qq)) > MARGIN) break;
            for (int dx = -s; dx <= s; ++dx) {
                const int ix = cx + dx;
                if (ix < 0 || ix > G - 1) continue;
                const int adx = dx < 0 ? -dx : dx;
                for (int dy = -s; dy <= s; ++dy) {
                    const int iy = cy + dy;
                    if (iy < 0 || iy > G - 1) continue;
                    const int ady = dy < 0 ? -dy : dy;
                    const int c0 = (ix * G + iy) * G;
                    #define SCANS(A_, E_)                                             \
                        for (int p2 = (A_) + l4; p2 < (E_); p2 += 4) {                \
                            const float4 T = tgt[p2];                                 \
                            const float d = fmaf(qx, T.x, fmaf(qy, T.y,               \
                                                 fmaf(qz, T.z, T.w)));                \
                            const ull cand = ((ull)f2key(d) << 32) | (uint32_t)p2;    \
                            pk = (cand < pk) ? cand : pk;                             \
                        }
                    if (max(adx, ady) == s) {
                        const int zl = max(cz - s, 0), zh = min(cz + s, G - 1);
                        const int a = cst[c0 + zl], e = cst[c0 + zh + 1];
                        SCANS(a, e)
                    } else {
                        const int z1 = cz - s;
                        if (z1 >= 0) { const int a = cst[c0 + z1], e = cst[c0 + z1 + 1]; SCANS(a, e) }
                        const int z2 = cz + s;
                        if (z2 <= G - 1) { const int a = cst[c0 + z2], e = cst[c0 + z2 + 1]; SCANS(a, e) }
                    }
                    #undef SCANS
                }
            }
            ull o = __shfl_xor(pk, 1); pk = (o < pk) ? o : pk;
            o = __shfl_xor(pk, 2);     pk = (o < pk) ? o : pk;
        }

        // residuals (exact: -0.5 * (-2t) == t bitwise)
        const int pos = (int)(uint32_t)pk;
        const float4 T = tgt[pos];
        const float rx = qx - (-0.5f * T.x);
        const float ry = qy - (-0.5f * T.y);
        const float rz = qz - (-0.5f * T.z);
        if (l4 < 3) {
            const uint32_t kk = (l4 == 0) ? f2key(rx) : ((l4 == 1) ? f2key(ry) : f2key(rz));
            kbuf[qi * 3 + l4] = kk;
        }
        if (l4 == 0) {
            s1a += (double)rx + (double)ry + (double)rz;
            s2a += (double)rx * rx + (double)ry * ry + (double)rz * rz;
        }
    }

    // block-reduce f64 partials
    {
        double a = s1a, c = s2a;
        #pragma unroll
        for (int off = 32; off; off >>= 1) { a += __shfl_down(a, off); c += __shfl_down(c, off); }
        if (lane == 0) { dm[wv] = a; dm[16 + wv] = c; }
    }
    __syncthreads();                          // keys + partials all visible
    double S = 0.0, S2 = 0.0;
    for (int k = 0; k < 16; ++k) { S += dm[k]; S2 += dm[16 + k]; }
    const double mu = S / NRES;
    const double var_all = (S2 - S * mu) / (NRES - 1);
    const double sd = sqrt(var_all > 0.0 ? var_all : 0.0);

    // ================= sigma: radix selection on LDS keys =================
    uint32_t key[12];
    #pragma unroll
    for (int e = 0; e < 12; ++e) key[e] = kbuf[e * 1024 + tid];
    uint32_t* rh = (uint32_t*)(smem + OFF_TGT);   // radix hists reuse tgt (free now)
    uint32_t* bc = um + 16;
    uint32_t* mr = um + 28;
    __syncthreads();                          // tgt reads done (residuals complete)

    // Level 1: 11-bit histogram
    rh[tid * 2] = 0u; rh[tid * 2 + 1] = 0u;
    __syncthreads();
    #pragma unroll
    for (int e = 0; e < 12; ++e) atomicAdd(&rh[key[e] >> 21], 1u);
    __syncthreads();
    scanB<2>(rh, um);
    psearchB<2>(rh, 2048, RANK_LO, NRES, bc + 0);
    psearchB<2>(rh, 2048, RANK_HI, NRES, bc + 3);
    __syncthreads();
    const uint32_t pA1 = bc[0], rA1 = RANK_LO - bc[1];
    const uint32_t pB1 = bc[3], rB1 = RANK_HI - bc[4];
    const uint32_t totA1 = bc[2] - bc[1], totB1 = bc[5] - bc[4];
    __syncthreads();

    // Level 2: two concurrent 11-bit histograms
    #pragma unroll
    for (int j = 0; j < 4; ++j) rh[tid * 4 + j] = 0u;
    __syncthreads();
    #pragma unroll
    for (int e = 0; e < 12; ++e) {
        const uint32_t k = key[e];
        const uint32_t pfx = k >> 21, bin = (k >> 10) & 2047u;
        if (pfx == pA1) atomicAdd(&rh[bin], 1u);
        if (pfx == pB1) atomicAdd(&rh[2048 + bin], 1u);
    }
    __syncthreads();
    scanB<2>(rh, um);
    scanB<2>(rh + 2048, um);
    psearchB<2>(rh, 2048, rA1, totA1, bc + 0);
    psearchB<2>(rh + 2048, 2048, rB1, totB1, bc + 3);
    __syncthreads();
    const uint32_t pA2 = (pA1 << 11) | bc[0], rA2 = rA1 - bc[1], totA2 = bc[2] - bc[1];
    const uint32_t pB2 = (pB1 << 11) | bc[3], rB2 = rB1 - bc[4], totB2 = bc[5] - bc[4];
    __syncthreads();

    // Level 3: two concurrent 10-bit histograms -> exact keys
    rh[tid * 2] = 0u; rh[tid * 2 + 1] = 0u;
    __syncthreads();
    #pragma unroll
    for (int e = 0; e < 12; ++e) {
        const uint32_t k = key[e];
        if ((k >> 10) == pA2) atomicAdd(&rh[k & 1023u], 1u);
        if ((k >> 10) == pB2) atomicAdd(&rh[1024 + (k & 1023u)], 1u);
    }
    __syncthreads();
    scanB<1>(rh, um);
    scanB<1>(rh + 1024, um);
    psearchB<1>(rh, 1024, rA2, totA2, bc + 0);
    psearchB<1>(rh + 1024, 1024, rB2, totB2, bc + 3);
    __syncthreads();
    const uint32_t k0 = (pA2 << 10) | bc[0];
    const uint32_t k2 = (pB2 << 10) | bc[3];
    const bool dup1 = (bc[2] >= rA2 + 2u);    // rank+1 shares key value?
    const bool dup3 = (bc[5] >= rB2 + 2u);

    // m-pass: min key strictly greater than k0 / k2
    uint32_t m1 = 0xFFFFFFFFu, m3 = 0xFFFFFFFFu;
    #pragma unroll
    for (int e = 0; e < 12; ++e) {
        const uint32_t k = key[e];
        if (k > k0 && k < m1) m1 = k;
        if (k > k2 && k < m3) m3 = k;
    }
    {
        uint32_t a = m1, c = m3;
        #pragma unroll
        for (int off = 32; off; off >>= 1) {
            const uint32_t ua = __shfl_down(a, off), uc = __shfl_down(c, off);
            a = (ua < a) ? ua : a; c = (uc < c) ? uc : c;
        }
        if (lane == 0) { mr[wv] = a; mr[16 + wv] = c; }
    }
    __syncthreads();
    uint32_t m1r = 0xFFFFFFFFu, m3r = 0xFFFFFFFFu;
    for (int k = 0; k < 16; ++k) {
        m1r = (mr[k] < m1r) ? mr[k] : m1r;
        m3r = (mr[16 + k] < m3r) ? mr[16 + k] : m3r;
    }
    const uint32_t k1 = dup1 ? k0 : m1r;
    const uint32_t k3 = dup3 ? k2 : m3r;

    // Linear-interpolated quantiles
    const double vl0 = (double)key2f(k0), vl1 = (double)key2f(k1);
    const double vh0 = (double)key2f(k2), vh1 = (double)key2f(k3);
    const double fr_lo = 0.15 * (NRES - 1) - (double)RANK_LO;
    const double fr_hi = 0.85 * (NRES - 1) - (double)RANK_HI;
    const float q_lo = (float)(vl0 + fr_lo * (vl1 - vl0));
    const float q_hi = (float)(vh0 + fr_hi * (vh1 - vh0));

    // B-pass: masked counts + sums + sumsq under both predicates
    int cq = 0, cs = 0;
    double sq = 0.0, ss = 0.0, sqq = 0.0, ssq = 0.0;
    #pragma unroll
    for (int e = 0; e < 12; ++e) {
        const float fv = key2f(key[e]);
        const double fd = (double)fv;
        if ((fv < q_lo) || (fv > q_hi)) { cq++; sq += fd; sqq += fd * fd; }
        if (fabs(fd - mu) > sd)         { cs++; ss += fd; ssq += fd * fd; }
    }
    {
        double a0 = sq, a1 = ss, a2 = sqq, a3 = ssq;
        int b0 = cq, b1 = cs;
        #pragma unroll
        for (int off = 32; off; off >>= 1) {
            a0 += __shfl_down(a0, off); a1 += __shfl_down(a1, off);
            a2 += __shfl_down(a2, off); a3 += __shfl_down(a3, off);
            b0 += __shfl_down(b0, off); b1 += __shfl_down(b1, off);
        }
        if (lane == 0) {
            dm[wv] = a0; dm[16 + wv] = a1; dm[32 + wv] = a2; dm[48 + wv] = a3;
            im[wv] = b0; im[16 + wv] = b1;
        }
    }
    __syncthreads();
    if (tid == 0) {
        double sq_t = 0, ss_t = 0, sqq_t = 0, ssq_t = 0;
        int cq_t = 0, cs_t = 0;
        for (int k = 0; k < 16; ++k) {
            sq_t += dm[k]; ss_t += dm[16 + k]; sqq_t += dm[32 + k]; ssq_t += dm[48 + k];
            cq_t += im[k]; cs_t += im[16 + k];
        }
        double cnt, sum, sumsq;
        if (cq_t > 0)      { cnt = cq_t;  sum = sq_t; sumsq = sqq_t; }
        else if (cs_t > 0) { cnt = cs_t;  sum = ss_t; sumsq = ssq_t; }
        else               { cnt = NRES;  sum = S;    sumsq = S2; }
        const double mean_w = sum / cnt;
        const double var = (sumsq - cnt * mean_w * mean_w) / (cnt - 1.0);
        const float sv = (float)sqrt(var > 0.0 ? var : 0.0);

        __hip_atomic_store(&sig[pd], sv, __ATOMIC_RELEASE, __HIP_MEMORY_SCOPE_AGENT);
        const unsigned prev = __hip_atomic_fetch_add(counter, 1u, __ATOMIC_ACQ_REL,
                                                     __HIP_MEMORY_SCOPE_AGENT);
        if (prev == NPAIR - 1) {              // final reduction (last pair)
            float m = 0.f;
            for (int i = 0; i < NB; ++i) {
                const float s0 = __hip_atomic_load(&sig[2 * i], __ATOMIC_ACQUIRE,
                                                   __HIP_MEMORY_SCOPE_AGENT);
                const float s1v = __hip_atomic_load(&sig[2 * i + 1], __ATOMIC_ACQUIRE,
                                                    __HIP_MEMORY_SCOPE_AGENT);
                m += fmaxf(s0, s1v);
            }
            out[0] = m / (float)NB;
        }
    }
}

extern "C" void kernel_launch(void* const* d_in, const int* in_sizes, int n_in,
                              void* d_out, int out_size, void* d_ws, size_t ws_size,
                              hipStream_t stream) {
    const float* x = (const float*)d_in[0];
    const float* y = (const float*)d_in[1];
    float*        sig     = (float*)d_ws;                     // 32 floats
    unsigned int* counter = (unsigned int*)((char*)d_ws + 128);
    hipMemsetAsync(counter, 0, 4, stream);
    fused_kernel<<<NPAIR, 1024, 0, stream>>>(x, y, sig, counter, (float*)d_out);
}

// Round 13
// 99.812 us; speedup vs baseline: 2.1367x; 2.1367x over previous
//
#include <hip/hip_runtime.h>
#include <stdint.h>
#include <math.h>

typedef unsigned short u16;
typedef unsigned long long ull;

// Problem constants (B=16, N=M=4096, D=3)
#define NPTS  4096
#define NB    16
#define NRES  12288               // residuals per (batch, direction)
#define NPAIR 32                  // 16 batches x 2 directions
#define SUBS  16                  // sub-blocks per pairdir (build duplicated)
#define QPB   256                 // queries per block (one quad round)
#define G     16                  // grid cells per axis
#define NCELL 4096                // G^3
#define HCEL  0.0625f             // 1/G
#define MARGIN 1e-5f
// 0-indexed order-statistic ranks for jnp.quantile(0.15/0.85, linear)
#define RANK_LO 1843u
#define RANK_HI 10443u

__device__ __forceinline__ uint32_t f2key(float f) {
    uint32_t u = __float_as_uint(f);
    return (u & 0x80000000u) ? ~u : (u | 0x80000000u);
}
__device__ __forceinline__ float key2f(uint32_t k) {
    uint32_t u = (k & 0x80000000u) ? (k ^ 0x80000000u) : ~k;
    return __uint_as_float(u);
}

// exclusive prefix over h[0 .. 1024*BPT), 1024 threads / 16 waves
template <int BPT>
__device__ __forceinline__ void scanB(uint32_t* h, uint32_t* wtmp) {
    const int tid = threadIdx.x, lane = tid & 63, wv = tid >> 6;
    const int base = tid * BPT;
    uint32_t loc[BPT], sum = 0;
    #pragma unroll
    for (int j = 0; j < BPT; ++j) { loc[j] = h[base + j]; sum += loc[j]; }
    uint32_t sc = sum;
    #pragma unroll
    for (int off = 1; off < 64; off <<= 1) {
        const uint32_t u = __shfl_up(sc, off);
        if (lane >= off) sc += u;
    }
    if (lane == 63) wtmp[wv] = sc;
    __syncthreads();
    uint32_t wb = 0;
    #pragma unroll
    for (int k = 0; k < 16; ++k) wb += (k < wv) ? wtmp[k] : 0u;
    uint32_t ex = wb + sc - sum;
    #pragma unroll
    for (int j = 0; j < BPT; ++j) { h[base + j] = ex; ex += loc[j]; }
    __syncthreads();
}

// unique bin with h[i] <= r < h[i+1] (exclusive-prefix array)
template <int BPT>
__device__ __forceinline__ void psearchB(const uint32_t* h, int n, uint32_t r,
                                         uint32_t total, uint32_t* out3) {
    const int base = threadIdx.x * BPT;
    #pragma unroll
    for (int j = 0; j < BPT; ++j) {
        const int i = base + j;
        if (i < n) {
            const uint32_t lo = h[i];
            const uint32_t hi = (i + 1 < n) ? h[i + 1] : total;
            if (lo <= r && r < hi) { out3[0] = (uint32_t)i; out3[1] = lo; out3[2] = hi; }
        }
    }
}

// ---------------------------------------------------------------------------
// Kernel 1: build+query. grid=(16 subs, 32 pds) x 1024 threads, ~72 KB LDS
// (2 blocks/CU, all 512 resident). Each block counting-sorts its pd's 4096
// targets into ITS OWN LDS copy (builds run in parallel across CUs), then
// answers 256 queries (quad-per-query, flattened cascade) from LDS.
// ---------------------------------------------------------------------------
__global__ __launch_bounds__(1024) void bq_kernel(const float* __restrict__ x,
                                                  const float* __restrict__ y,
                                                  uint32_t* __restrict__ keys,
                                                  double* __restrict__ partials,
                                                  unsigned int* __restrict__ counters) {
    __shared__ __align__(16) float4 tgt[NPTS];      // 64 KB (first 16 KB alias hist)
    __shared__ u16 cst[NCELL + 64];                 // 8.3 KB
    __shared__ uint32_t um[16];
    __shared__ double wred[32];
    uint32_t* hist = (uint32_t*)tgt;

    const int pd = blockIdx.y, b = pd >> 1, dir = pd & 1;
    const float* tg = (dir == 0 ? y : x) + (size_t)b * NPTS * 3;   // targets
    const float* qg = (dir == 0 ? x : y) + (size_t)b * NPTS * 3;   // queries
    const int tid = threadIdx.x, lane = tid & 63, wv = tid >> 6;

    // ---------------- build (duplicated per sub-block) ----------------
    #pragma unroll
    for (int j = 0; j < 4; ++j) hist[tid * 4 + j] = 0u;
    __syncthreads();

    float f[12];
    int ci[4];
    {
        const float4* tp4 = reinterpret_cast<const float4*>(tg + (size_t)tid * 12);
        #pragma unroll
        for (int j = 0; j < 3; ++j) {
            const float4 v = tp4[j];
            f[j * 4 + 0] = v.x; f[j * 4 + 1] = v.y; f[j * 4 + 2] = v.z; f[j * 4 + 3] = v.w;
        }
        #pragma unroll
        for (int k = 0; k < 4; ++k) {
            const int cx = (int)(f[k * 3 + 0] * 16.f);
            const int cy = (int)(f[k * 3 + 1] * 16.f);
            const int cz = (int)(f[k * 3 + 2] * 16.f);
            ci[k] = (cx * G + cy) * G + cz;
            atomicAdd(&hist[ci[k]], 1u);
        }
    }
    __syncthreads();
    scanB<4>(hist, um);                       // exclusive prefix of 4096 bins
    for (int i = tid; i <= NCELL; i += 1024)
        cst[i] = (u16)((i == NCELL) ? NPTS : hist[i]);
    __syncthreads();
    uint32_t pos4[4];
    #pragma unroll
    for (int k = 0; k < 4; ++k) pos4[k] = atomicAdd(&hist[ci[k]], 1u);
    __syncthreads();                          // all hist use done; tgt may overwrite
    #pragma unroll
    for (int k = 0; k < 4; ++k) {
        const float px = f[k * 3 + 0], py = f[k * 3 + 1], pz = f[k * 3 + 2];
        const float w = fmaf(pz, pz, fmaf(py, py, px * px));
        tgt[pos4[k]] = make_float4(-2.f * px, -2.f * py, -2.f * pz, w);
    }
    __syncthreads();                          // build complete

    // ---------------- query: one quad round (256 queries) ----------------
    const int l4 = tid & 3;
    const int qi = blockIdx.x * QPB + (tid >> 2);
    const float qx = qg[qi * 3 + 0], qy = qg[qi * 3 + 1], qz = qg[qi * 3 + 2];
    const float qq = fmaf(qz, qz, fmaf(qy, qy, qx * qx));
    const int cx = (int)(qx * 16.f), cy = (int)(qy * 16.f), cz = (int)(qz * 16.f);

    ull pk = ~0ull;
    {   // 9 clamped z-runs, flattened quad-strided cascade loop
        const int zlo = max(cz - 1, 0), zhi = min(cz + 1, G - 1);
        #define RUNB(RR, AV, NV)                                              \
            int AV, NV;                                                       \
            { const int ix = min(max(cx + (RR) / 3 - 1, 0), G - 1);           \
              const int iy = min(max(cy + (RR) % 3 - 1, 0), G - 1);           \
              const int cc = (ix * G + iy) * G;                               \
              AV = cst[cc + zlo];                                             \
              NV = cst[cc + zhi + 1] - AV; }
        RUNB(0, a0, n0) RUNB(1, a1, n1) RUNB(2, a2, n2)
        RUNB(3, a3, n3) RUNB(4, a4, n4) RUNB(5, a5, n5)
        RUNB(6, a6, n6) RUNB(7, a7, n7) RUNB(8, a8, n8)
        #undef RUNB
        const int nc = n0 + n1 + n2 + n3 + n4 + n5 + n6 + n7 + n8;
        for (int li = l4; li < nc; li += 4) {
            int pos;
            {
                int rem = li; pos = a0 + rem;
                rem -= n0; pos = (rem >= 0) ? a1 + rem : pos;
                rem -= n1; pos = (rem >= 0) ? a2 + rem : pos;
                rem -= n2; pos = (rem >= 0) ? a3 + rem : pos;
                rem -= n3; pos = (rem >= 0) ? a4 + rem : pos;
                rem -= n4; pos = (rem >= 0) ? a5 + rem : pos;
                rem -= n5; pos = (rem >= 0) ? a6 + rem : pos;
                rem -= n6; pos = (rem >= 0) ? a7 + rem : pos;
                rem -= n7; pos = (rem >= 0) ? a8 + rem : pos;
                pos = min(pos, NPTS - 1);
            }
            const float4 T = tgt[pos];
            const float d = fmaf(qx, T.x, fmaf(qy, T.y, fmaf(qz, T.z, T.w)));
            const ull cand = ((ull)f2key(d) << 32) | (uint32_t)pos;
            pk = (cand < pk) ? cand : pk;
        }
    }
    {   // quad min-reduce
        ull o = __shfl_xor(pk, 1); pk = (o < pk) ? o : pk;
        o = __shfl_xor(pk, 2);     pk = (o < pk) ? o : pk;
    }
    // shell expansion while min possible distance could beat current best
    for (int s = 2; s <= G - 1; ++s) {
        const float bd = key2f((uint32_t)(pk >> 32));
        const float dmin = (float)(s - 1) * HCEL;
        if (fmaf(dmin, dmin, -(bd + qq)) > MARGIN) break;
        for (int dx = -s; dx <= s; ++dx) {
            const int ix = cx + dx;
            if (ix < 0 || ix > G - 1) continue;
            const int adx = dx < 0 ? -dx : dx;
            for (int dy = -s; dy <= s; ++dy) {
                const int iy = cy + dy;
                if (iy < 0 || iy > G - 1) continue;
                const int ady = dy < 0 ? -dy : dy;
                const int c0 = (ix * G + iy) * G;
                #define SCANS(A_, E_)                                             \
                    for (int p2 = (A_) + l4; p2 < (E_); p2 += 4) {                \
                        const float4 T = tgt[p2];                                 \
                        const float d = fmaf(qx, T.x, fmaf(qy, T.y,               \
                                             fmaf(qz, T.z, T.w)));                \
                        const ull cand = ((ull)f2key(d) << 32) | (uint32_t)p2;    \
                        pk = (cand < pk) ? cand : pk;                             \
                    }
                if (max(adx, ady) == s) {
                    const int zl = max(cz - s, 0), zh = min(cz + s, G - 1);
                    const int a = cst[c0 + zl], e = cst[c0 + zh + 1];
                    SCANS(a, e)
                } else {
                    const int z1 = cz - s;
                    if (z1 >= 0) { const int a = cst[c0 + z1], e = cst[c0 + z1 + 1]; SCANS(a, e) }
                    const int z2 = cz + s;
                    if (z2 <= G - 1) { const int a = cst[c0 + z2], e = cst[c0 + z2 + 1]; SCANS(a, e) }
                }
                #undef SCANS
            }
        }
        ull o = __shfl_xor(pk, 1); pk = (o < pk) ? o : pk;
        o = __shfl_xor(pk, 2);     pk = (o < pk) ? o : pk;
    }

    // residuals (exact: -0.5 * (-2t) == t bitwise)
    const int pos = (int)(uint32_t)pk;
    const float4 T = tgt[pos];
    const float rx = qx - (-0.5f * T.x);
    const float ry = qy - (-0.5f * T.y);
    const float rz = qz - (-0.5f * T.z);
    if (l4 < 3) {
        const uint32_t kk = (l4 == 0) ? f2key(rx) : ((l4 == 1) ? f2key(ry) : f2key(rz));
        keys[(size_t)pd * NRES + (size_t)qi * 3 + l4] = kk;
    }

    // f64 partial sums (lane 0 of each quad)
    double s1 = 0.0, s2 = 0.0;
    if (l4 == 0) {
        s1 = (double)rx + (double)ry + (double)rz;
        s2 = (double)rx * rx + (double)ry * ry + (double)rz * rz;
    }
    #pragma unroll
    for (int off = 32; off; off >>= 1) { s1 += __shfl_down(s1, off); s2 += __shfl_down(s2, off); }
    if (lane == 0) { wred[wv] = s1; wred[16 + wv] = s2; }
    __syncthreads();
    if (tid == 0) {
        double a = 0.0, c = 0.0;
        for (int k = 0; k < 16; ++k) { a += wred[k]; c += wred[16 + k]; }
        partials[(size_t)pd * 32 + blockIdx.x]      = a;    // s   [0..15]
        partials[(size_t)pd * 32 + 16 + blockIdx.x] = c;    // s2  [16..31]
    }
    if (pd == 0 && blockIdx.x == 0 && tid == 1) counters[0] = 0u;
}

// ---------------------------------------------------------------------------
// Kernel 2: robust masked std + fused final. 32 blocks x 1024 threads.
// (r11-proven structure; only the partials reduce changed to 16+16.)
// ---------------------------------------------------------------------------
__global__ __launch_bounds__(1024) void sigma_kernel(const uint32_t* __restrict__ keysg,
                                                     const double* __restrict__ partials,
                                                     float* __restrict__ sig,
                                                     unsigned int* __restrict__ counters,
                                                     float* __restrict__ out) {
    __shared__ uint32_t hist[4096];            // 16 KB
    __shared__ uint32_t wtmp[16];
    __shared__ uint32_t bc[12];
    __shared__ double dr[64];
    __shared__ int io[32];
    __shared__ uint32_t um[32];

    const int pair = blockIdx.x;
    const int tid = threadIdx.x, lane = tid & 63, wv = tid >> 6;

    // keys into registers (coalesced, 12/thread)
    uint32_t key[12];
    const uint32_t* kp = keysg + (size_t)pair * NRES;
    #pragma unroll
    for (int e = 0; e < 12; ++e) key[e] = kp[e * 1024 + tid];

    // S, S2 from 16+16 partials
    if (tid < 32) {
        double a = partials[(size_t)pair * 32 + tid];
        #pragma unroll
        for (int off = 8; off; off >>= 1) a += __shfl_down(a, off);
        if (tid == 0)  dr[0] = a;
        if (tid == 16) dr[1] = a;
    }
    __syncthreads();
    const double S = dr[0], S2 = dr[1];
    const double mu = S / NRES;
    const double var_all = (S2 - S * mu) / (NRES - 1);
    const double sd = sqrt(var_all > 0.0 ? var_all : 0.0);
    __syncthreads();

    // ---- Level 1: 11-bit histogram from register keys ----
    hist[tid * 2] = 0u; hist[tid * 2 + 1] = 0u;
    __syncthreads();
    #pragma unroll
    for (int e = 0; e < 12; ++e) atomicAdd(&hist[key[e] >> 21], 1u);
    __syncthreads();
    scanB<2>(hist, wtmp);
    psearchB<2>(hist, 2048, RANK_LO, NRES, bc + 0);
    psearchB<2>(hist, 2048, RANK_HI, NRES, bc + 3);
    __syncthreads();
    const uint32_t pA1 = bc[0], rA1 = RANK_LO - bc[1], totA1 = bc[2] - bc[1];
    const uint32_t pB1 = bc[3], rB1 = RANK_HI - bc[4], totB1 = bc[5] - bc[4];
    __syncthreads();

    // ---- Level 2: two concurrent 11-bit histograms ----
    #pragma unroll
    for (int j = 0; j < 4; ++j) hist[tid * 4 + j] = 0u;
    __syncthreads();
    #pragma unroll
    for (int e = 0; e < 12; ++e) {
        const uint32_t k = key[e];
        const uint32_t pfx = k >> 21, bin = (k >> 10) & 2047u;
        if (pfx == pA1) atomicAdd(&hist[bin], 1u);
        if (pfx == pB1) atomicAdd(&hist[2048 + bin], 1u);
    }
    __syncthreads();
    scanB<2>(hist, wtmp);
    scanB<2>(hist + 2048, wtmp);
    psearchB<2>(hist, 2048, rA1, totA1, bc + 0);
    psearchB<2>(hist + 2048, 2048, rB1, totB1, bc + 3);
    __syncthreads();
    const uint32_t pA2 = (pA1 << 11) | bc[0], rA2 = rA1 - bc[1], totA2 = bc[2] - bc[1];
    const uint32_t pB2 = (pB1 << 11) | bc[3], rB2 = rB1 - bc[4], totB2 = bc[5] - bc[4];
    __syncthreads();

    // ---- Level 3: two concurrent 10-bit histograms -> exact keys ----
    hist[tid * 2] = 0u; hist[tid * 2 + 1] = 0u;
    __syncthreads();
    #pragma unroll
    for (int e = 0; e < 12; ++e) {
        const uint32_t k = key[e];
        if ((k >> 10) == pA2) atomicAdd(&hist[k & 1023u], 1u);
        if ((k >> 10) == pB2) atomicAdd(&hist[1024 + (k & 1023u)], 1u);
    }
    __syncthreads();
    scanB<1>(hist, wtmp);
    scanB<1>(hist + 1024, wtmp);
    psearchB<1>(hist, 1024, rA2, totA2, bc + 0);
    psearchB<1>(hist + 1024, 1024, rB2, totB2, bc + 3);
    __syncthreads();
    const uint32_t k0 = (pA2 << 10) | bc[0];
    const uint32_t k2 = (pB2 << 10) | bc[3];
    const bool dup1 = (bc[2] >= rA2 + 2u);
    const bool dup3 = (bc[5] >= rB2 + 2u);

    // ---- m-pass: min key strictly greater than k0 / k2 ----
    uint32_t m1 = 0xFFFFFFFFu, m3 = 0xFFFFFFFFu;
    #pragma unroll
    for (int e = 0; e < 12; ++e) {
        const uint32_t k = key[e];
        if (k > k0 && k < m1) m1 = k;
        if (k > k2 && k < m3) m3 = k;
    }
    {
        uint32_t a = m1, c = m3;
        #pragma unroll
        for (int off = 32; off; off >>= 1) {
            const uint32_t ua = __shfl_down(a, off), uc = __shfl_down(c, off);
            a = (ua < a) ? ua : a; c = (uc < c) ? uc : c;
        }
        if (lane == 0) { um[wv] = a; um[16 + wv] = c; }
    }
    __syncthreads();
    uint32_t m1r = 0xFFFFFFFFu, m3r = 0xFFFFFFFFu;
    for (int k = 0; k < 16; ++k) {
        m1r = (um[k] < m1r) ? um[k] : m1r;
        m3r = (um[16 + k] < m3r) ? um[16 + k] : m3r;
    }
    const uint32_t k1 = dup1 ? k0 : m1r;
    const uint32_t k3 = dup3 ? k2 : m3r;

    // Linear-interpolated quantiles
    const double vl0 = (double)key2f(k0), vl1 = (double)key2f(k1);
    const double vh0 = (double)key2f(k2), vh1 = (double)key2f(k3);
    const double fr_lo = 0.15 * (NRES - 1) - (double)RANK_LO;
    const double fr_hi = 0.85 * (NRES - 1) - (double)RANK_HI;
    const float q_lo = (float)(vl0 + fr_lo * (vl1 - vl0));
    const float q_hi = (float)(vh0 + fr_hi * (vh1 - vh0));

    // ---- B-pass: masked counts + sums + sumsq under both predicates ----
    int cq = 0, cs = 0;
    double sq = 0.0, ss = 0.0, sqq = 0.0, ssq = 0.0;
    #pragma unroll
    for (int e = 0; e < 12; ++e) {
        const float fv = key2f(key[e]);
        const double fd = (double)fv;
        if ((fv < q_lo) || (fv > q_hi)) { cq++; sq += fd; sqq += fd * fd; }
        if (fabs(fd - mu) > sd)         { cs++; ss += fd; ssq += fd * fd; }
    }
    {
        double a0 = sq, a1 = ss, a2 = sqq, a3 = ssq;
        int b0 = cq, b1 = cs;
        #pragma unroll
        for (int off = 32; off; off >>= 1) {
            a0 += __shfl_down(a0, off); a1 += __shfl_down(a1, off);
            a2 += __shfl_down(a2, off); a3 += __shfl_down(a3, off);
            b0 += __shfl_down(b0, off); b1 += __shfl_down(b1, off);
        }
        if (lane == 0) {
            dr[wv] = a0; dr[16 + wv] = a1; dr[32 + wv] = a2; dr[48 + wv] = a3;
            io[wv] = b0; io[16 + wv] = b1;
        }
    }
    __syncthreads();
    if (tid == 0) {
        double sq_t = 0, ss_t = 0, sqq_t = 0, ssq_t = 0;
        int cq_t = 0, cs_t = 0;
        for (int k = 0; k < 16; ++k) {
            sq_t += dr[k]; ss_t += dr[16 + k]; sqq_t += dr[32 + k]; ssq_t += dr[48 + k];
            cq_t += io[k]; cs_t += io[16 + k];
        }
        double cnt, sum, sumsq;
        if (cq_t > 0)      { cnt = cq_t;  sum = sq_t; sumsq = sqq_t; }
        else if (cs_t > 0) { cnt = cs_t;  sum = ss_t; sumsq = ssq_t; }
        else               { cnt = NRES;  sum = S;    sumsq = S2; }
        const double mean_w = sum / cnt;
        const double var = (sumsq - cnt * mean_w * mean_w) / (cnt - 1.0);
        const float sv = (float)sqrt(var > 0.0 ? var : 0.0);

        __hip_atomic_store(&sig[pair], sv, __ATOMIC_RELEASE, __HIP_MEMORY_SCOPE_AGENT);
        const unsigned prev = __hip_atomic_fetch_add(&counters[0], 1u,
                                                     __ATOMIC_ACQ_REL,
                                                     __HIP_MEMORY_SCOPE_AGENT);
        if (prev == NPAIR - 1) {
            float m = 0.f;
            for (int i = 0; i < NB; ++i) {
                const float s0 = __hip_atomic_load(&sig[2 * i], __ATOMIC_ACQUIRE,
                                                   __HIP_MEMORY_SCOPE_AGENT);
                const float s1v = __hip_atomic_load(&sig[2 * i + 1], __ATOMIC_ACQUIRE,
                                                    __HIP_MEMORY_SCOPE_AGENT);
                m += fmaxf(s0, s1v);
            }
            out[0] = m / (float)NB;
        }
    }
}

extern "C" void kernel_launch(void* const* d_in, const int* in_sizes, int n_in,
                              void* d_out, int out_size, void* d_ws, size_t ws_size,
                              hipStream_t stream) {
    const float* x = (const float*)d_in[0];
    const float* y = (const float*)d_in[1];
    char* w = (char*)d_ws;
    uint32_t*     keys     = (uint32_t*)(w);                  // 1.5 MB
    double*       partials = (double*)(w + 1572864);          // 8 KB (32 x 32 f64)
    float*        sig      = (float*)(w + 1581056);           // 128 B
    unsigned int* counters = (unsigned int*)(w + 1581184);    // 128 B

    bq_kernel<<<dim3(SUBS, NPAIR), 1024, 0, stream>>>(x, y, keys, partials, counters);
    sigma_kernel<<<NPAIR, 1024, 0, stream>>>(keys, partials, sig, counters,
                                             (float*)d_out);
}